// Round 10
// baseline (841.460 us; speedup 1.0000x reference)
//
#include <hip/hip_runtime.h>
#include <hip/hip_bf16.h>

#define N_NODES 100000
#define N_EDGES 1600000
#define F_IN_DIM 100
#define F_IN_PAD 104     // padded bf16 row stride (13 x 16B chunks)
#define H_DIM 256
#define BN_DIM 128
#define N_LABELS 19
#define BN_EPS 1e-5f

// bucket-partitioned CSR build
#define BUCKET_SHIFT 8
#define NB 391           // ceil(100000 / 256) buckets of 256 nodes
#define EPB 4096         // edges per partition block
#define PB 391           // ceil(1600000 / 4096) partition blocks

typedef __attribute__((ext_vector_type(8))) short bf16x8;   // 4 VGPRs, MFMA A/B frag / 16B
typedef __attribute__((ext_vector_type(4))) float f32x4;    // MFMA C/D frag

static __device__ inline short f2bf(float f) {
    __hip_bfloat16 h = __float2bfloat16(f);
    return *(short*)&h;
}
static __device__ inline float bf2f(short s) {
    unsigned u = ((unsigned)(unsigned short)s) << 16;
    return __builtin_bit_cast(float, u);
}

// ---------------------------------------------------------------- CSR build (bucketed)
__global__ __launch_bounds__(256) void part_hist_kernel(const int* __restrict__ dst,
                                                        int* __restrict__ part_hist, int E)
{
    __shared__ int h[NB];
    int tid = threadIdx.x;
    for (int i = tid; i < NB; i += 256) h[i] = 0;
    __syncthreads();
    int base = blockIdx.x * EPB;
    int end = min(base + EPB, E);
    for (int e = base + tid; e < end; e += 256)
        atomicAdd(&h[dst[e] >> BUCKET_SHIFT], 1);
    __syncthreads();
    for (int i = tid; i < NB; i += 256) part_hist[blockIdx.x * NB + i] = h[i];
}

__global__ __launch_bounds__(512) void bucket_total_kernel(const int* __restrict__ part_hist,
                                                           int* __restrict__ bucket_total)
{
    __shared__ int ls[512];
    int b = blockIdx.x;
    int s = 0;
    for (int p = threadIdx.x; p < PB; p += 512) s += part_hist[p * NB + b];
    ls[threadIdx.x] = s;
    __syncthreads();
    for (int off = 256; off > 0; off >>= 1) {
        if (threadIdx.x < off) ls[threadIdx.x] += ls[threadIdx.x + off];
        __syncthreads();
    }
    if (threadIdx.x == 0) bucket_total[b] = ls[0];
}

__global__ __launch_bounds__(512) void bucket_scan_kernel(const int* __restrict__ bucket_total,
                                                          int* __restrict__ bucket_base)
{
    __shared__ int ls[512];
    int tid = threadIdx.x;
    ls[tid] = (tid < NB) ? bucket_total[tid] : 0;
    __syncthreads();
    for (int off = 1; off < 512; off <<= 1) {
        int v = ls[tid];
        int add = (tid >= off) ? ls[tid - off] : 0;
        __syncthreads();
        ls[tid] = v + add;
        __syncthreads();
    }
    if (tid < NB) bucket_base[tid] = (tid > 0) ? ls[tid - 1] : 0;
    if (tid == 0) bucket_base[NB] = ls[NB - 1];
}

__global__ __launch_bounds__(512) void part_offset_kernel(int* __restrict__ part_hist,
                                                          const int* __restrict__ bucket_base)
{
    __shared__ int ls[512];
    int b = blockIdx.x;
    int tid = threadIdx.x;
    int v = (tid < PB) ? part_hist[tid * NB + b] : 0;
    ls[tid] = v;
    __syncthreads();
    for (int off = 1; off < 512; off <<= 1) {
        int x = ls[tid];
        int add = (tid >= off) ? ls[tid - off] : 0;
        __syncthreads();
        ls[tid] = x + add;
        __syncthreads();
    }
    if (tid < PB) part_hist[tid * NB + b] = bucket_base[b] + ((tid > 0) ? ls[tid - 1] : 0);
}

__global__ __launch_bounds__(256) void partition_kernel(const int* __restrict__ src,
                                                        const int* __restrict__ dst,
                                                        const int* __restrict__ part_hist,
                                                        int* __restrict__ ep, int E)
{
    __shared__ int cur[NB];
    int tid = threadIdx.x;
    for (int i = tid; i < NB; i += 256) cur[i] = part_hist[blockIdx.x * NB + i];
    __syncthreads();
    int base = blockIdx.x * EPB;
    int end = min(base + EPB, E);
    for (int e = base + tid; e < end; e += 256) {
        int d = dst[e];
        int s = src[e];
        int pos = atomicAdd(&cur[d >> BUCKET_SHIFT], 1);
        ep[pos] = (s << 8) | (d & 255);
    }
}

__global__ __launch_bounds__(256) void bucket_csr_kernel(const int* __restrict__ ep,
                                                         const int* __restrict__ bucket_base,
                                                         int* __restrict__ row_start,
                                                         float* __restrict__ dinv,
                                                         int* __restrict__ src_sorted, int N, int E)
{
    __shared__ int h[256], sc[256], cur[256];
    int b = blockIdx.x;
    int tid = threadIdx.x;
    int e0 = bucket_base[b], e1 = bucket_base[b + 1];
    int node0 = b << BUCKET_SHIFT;
    int nn = min(256, N - node0);

    h[tid] = 0;
    __syncthreads();
    for (int e = e0 + tid; e < e1; e += 256)
        atomicAdd(&h[ep[e] & 255], 1);
    __syncthreads();

    sc[tid] = h[tid];
    __syncthreads();
    for (int off = 1; off < 256; off <<= 1) {
        int v = sc[tid];
        int add = (tid >= off) ? sc[tid - off] : 0;
        __syncthreads();
        sc[tid] = v + add;
        __syncthreads();
    }
    int excl = e0 + ((tid > 0) ? sc[tid - 1] : 0);
    if (tid < nn) {
        row_start[node0 + tid] = excl;
        dinv[node0 + tid] = rsqrtf((float)h[tid] + 1.0f);
    }
    cur[tid] = excl;
    __syncthreads();
    for (int e = e0 + tid; e < e1; e += 256) {
        int p = ep[e];
        int pos = atomicAdd(&cur[p & 255], 1);
        src_sorted[pos] = ((unsigned)p) >> 8;
    }
    if (b == 0 && tid == 0) row_start[N] = E;
}

// ---------------------------------------------------------------- weight pack (all 5 in one)
__global__ __launch_bounds__(256) void pack_all(
    const float* __restrict__ W1, const float* __restrict__ W2, const float* __restrict__ W3,
    const float* __restrict__ Wf1, const float* __restrict__ Wf2a,
    short* __restrict__ Wt1, short* __restrict__ Wt2, short* __restrict__ Wt3,
    short* __restrict__ Wtf1, short* __restrict__ Wtf2a)
{
    int idx = blockIdx.x * 256 + threadIdx.x;
    const float* W; short* Wt; int K, N, Kp, local;
    if (idx < 10400)       { W = W1;   Wt = Wt1;   K = 100; N = 100; Kp = 104; local = idx; }
    else if (idx < 20800)  { W = W2;   Wt = Wt2;   K = 100; N = 100; Kp = 104; local = idx - 10400; }
    else if (idx < 47424)  { W = W3;   Wt = Wt3;   K = 100; N = 256; Kp = 104; local = idx - 20800; }
    else if (idx < 112960) { W = Wf1;  Wt = Wtf1;  K = 256; N = 256; Kp = 256; local = idx - 47424; }
    else if (idx < 145728) { W = Wf2a; Wt = Wtf2a; K = 256; N = 128; Kp = 256; local = idx - 112960; }
    else return;
    int n = local / Kp, k = local - n * Kp;
    Wt[local] = (k < K) ? f2bf(W[(size_t)k * N + n]) : (short)0;
}

// ---------------------------------------------------------------- register-blocked direct MFMA GEMM
// No LDS, no barriers. One wave per 64-row tile (4 sub-frags of 16 rows);
// per K-chunk: 4 A-frags + NC B-frags from global (B L2-resident), 4*NC MFMAs.
// acc = 4*NC f32x4 regs -> large VGPR allocation = deep load pipeline.
// A-frag layout: A[m=lane&15][k=quad*8+j]; C/D: col=lane&15, row=quad*4+reg.
template<int ABF16, int NC, int KC>
__global__ __launch_bounds__(256) void gemm_reg(
    const void* __restrict__ Av, const short* __restrict__ Wt,
    const float* __restrict__ bias, const float* __restrict__ rowscale,
    short* __restrict__ C, int M, int K, int Kp, int Nout,
    int strideA, int strideC, int relu)
{
    int tid = threadIdx.x;
    int wv = tid >> 6;
    int lane = tid & 63;
    int quad = lane >> 4, l15 = lane & 15;
    int tile = blockIdx.x * 4 + wv;
    int m0 = tile << 6;                      // 64 rows per wave
    if (m0 >= M) return;
    int colBase = blockIdx.y * (NC * 16);

    f32x4 acc[4][NC];
    #pragma unroll
    for (int im = 0; im < 4; im++)
        #pragma unroll
        for (int nc = 0; nc < NC; nc++)
            acc[im][nc] = (f32x4){0.f, 0.f, 0.f, 0.f};

    int rows[4]; bool rok[4];
    #pragma unroll
    for (int im = 0; im < 4; im++) {
        rows[im] = m0 + im * 16 + l15;
        rok[im] = rows[im] < M;
    }

    const short* Ab = (const short*)Av;
    const float* Af = (const float*)Av;

    #pragma unroll
    for (int kc = 0; kc < KC; kc++) {
        int off = kc * 32 + quad * 8;
        bf16x8 b[NC];
        #pragma unroll
        for (int nc = 0; nc < NC; nc++) {
            int col = colBase + nc * 16 + l15;
            b[nc] = (bf16x8){0,0,0,0,0,0,0,0};
            if (col < Nout && off + 8 <= Kp)
                b[nc] = *(const bf16x8*)(Wt + (size_t)col * Kp + off);
        }
        bf16x8 a[4];
        #pragma unroll
        for (int im = 0; im < 4; im++) {
            a[im] = (bf16x8){0,0,0,0,0,0,0,0};
            if (ABF16) {
                if (rok[im] && off + 8 <= Kp)
                    a[im] = *(const bf16x8*)(Ab + (size_t)rows[im] * strideA + off);
            } else {
                float4 v0 = make_float4(0.f,0.f,0.f,0.f), v1 = v0;
                const float* Ar = Af + (size_t)rows[im] * strideA;
                if (rok[im] && off + 4 <= K) v0 = *(const float4*)(Ar + off);
                if (rok[im] && off + 8 <= K) v1 = *(const float4*)(Ar + off + 4);
                v0.x = fminf(fmaxf(v0.x, -0.4f), 0.4f);
                v0.y = fminf(fmaxf(v0.y, -0.4f), 0.4f);
                v0.z = fminf(fmaxf(v0.z, -0.4f), 0.4f);
                v0.w = fminf(fmaxf(v0.w, -0.4f), 0.4f);
                v1.x = fminf(fmaxf(v1.x, -0.4f), 0.4f);
                v1.y = fminf(fmaxf(v1.y, -0.4f), 0.4f);
                v1.z = fminf(fmaxf(v1.z, -0.4f), 0.4f);
                v1.w = fminf(fmaxf(v1.w, -0.4f), 0.4f);
                a[im][0] = f2bf(v0.x); a[im][1] = f2bf(v0.y);
                a[im][2] = f2bf(v0.z); a[im][3] = f2bf(v0.w);
                a[im][4] = f2bf(v1.x); a[im][5] = f2bf(v1.y);
                a[im][6] = f2bf(v1.z); a[im][7] = f2bf(v1.w);
            }
        }
        #pragma unroll
        for (int im = 0; im < 4; im++)
            #pragma unroll
            for (int nc = 0; nc < NC; nc++)
                acc[im][nc] = __builtin_amdgcn_mfma_f32_16x16x32_bf16(
                    a[im], b[nc], acc[im][nc], 0, 0, 0);
    }

    // ---- epilogue
    #pragma unroll
    for (int im = 0; im < 4; im++) {
        float rs[4];
        #pragma unroll
        for (int reg = 0; reg < 4; reg++) {
            int r = m0 + im * 16 + quad * 4 + reg;
            rs[reg] = (rowscale && r < M) ? rowscale[r] : 1.f;
        }
        #pragma unroll
        for (int nc = 0; nc < NC; nc++) {
            int col = colBase + nc * 16 + l15;
            if (col >= strideC) continue;
            bool cvalid = col < Nout;
            float bv = (bias && cvalid) ? bias[col] : 0.f;
            #pragma unroll
            for (int reg = 0; reg < 4; reg++) {
                int r = m0 + im * 16 + quad * 4 + reg;
                if (r >= M) continue;
                float v = 0.f;
                if (cvalid) {
                    v = (acc[im][nc][reg] + bv) * rs[reg];
                    if (relu) v = fmaxf(v, 0.f);
                }
                C[(size_t)r * strideC + col] = f2bf(v);
            }
        }
    }
}

// ---------------------------------------------------------------- gather aggregation (bf16)
// MODE 0: out = relu(di*(acc+self) + bias)           (conv1)
// MODE 1: out = di * relu(di*(acc+self) + bias)      (conv2: pre-folds next layer's dinv_s)
// MODE 2: out = di * (acc+self)                      (conv3 pre-aggregation)
template<int F, int STRIDE, int T, int MODE>
__global__ void gather_kernel(const short* __restrict__ xws,
                              const int* __restrict__ row_start,
                              const int* __restrict__ src_sorted,
                              const float* __restrict__ dinv,
                              const float* __restrict__ bias,
                              short* __restrict__ out, int n)
{
    constexpr int CHUNKS = STRIDE / 8;
    int group = (blockIdx.x * blockDim.x + threadIdx.x) / T;
    int lane = threadIdx.x % T;
    if (group >= n) return;
    int d = group;
    int e0 = row_start[d], e1 = row_start[d + 1];
    bool active = (lane < CHUNKS);
    int coff = lane * 8;
    float acc[8] = {};
    for (int e = e0; e < e1; e++) {
        int s = src_sorted[e];
        if (active) {
            bf16x8 v = *(const bf16x8*)(xws + (size_t)s * STRIDE + coff);
            #pragma unroll
            for (int j = 0; j < 8; j++) acc[j] += bf2f(v[j]);
        }
    }
    if (active) {
        bf16x8 xv = *(const bf16x8*)(xws + (size_t)d * STRIDE + coff);
        float di = dinv[d];
        bf16x8 o;
        #pragma unroll
        for (int j = 0; j < 8; j++) {
            int col = coff + j;
            float v = 0.f;
            if (col < F) {
                v = di * (acc[j] + bf2f(xv[j]));
                if (MODE == 0) v = fmaxf(v + bias[col], 0.f);
                if (MODE == 1) v = di * fmaxf(v + bias[col], 0.f);
            }
            o[j] = f2bf(v);
        }
        *(bf16x8*)(out + (size_t)d * STRIDE + coff) = o;
    }
}

// ---------------------------------------------------------------- BN stats (bf16 input)
__global__ void bn_stats_kernel(const short* __restrict__ h,
                                float* __restrict__ sum, float* __restrict__ sumsq, int Ntot)
{
    int c = threadIdx.x & 127;
    int rpb = blockDim.x >> 7;
    int r0 = blockIdx.x * rpb + (threadIdx.x >> 7);
    int stride = gridDim.x * rpb;
    float s = 0.f, ss = 0.f;
    for (int r = r0; r < Ntot; r += stride) {
        float v = bf2f(h[(size_t)r * BN_DIM + c]);
        s += v; ss += v * v;
    }
    __shared__ float ls[256], lss[256];
    ls[threadIdx.x] = s; lss[threadIdx.x] = ss;
    __syncthreads();
    if (threadIdx.x < 128) {
        s = ls[threadIdx.x] + ls[threadIdx.x + 128];
        ss = lss[threadIdx.x] + lss[threadIdx.x + 128];
        atomicAdd(&sum[c], s);
        atomicAdd(&sumsq[c], ss);
    }
}

__global__ void bn_finalize_kernel(const float* __restrict__ sum, const float* __restrict__ sumsq,
                                   const float* __restrict__ gamma, const float* __restrict__ beta,
                                   float* __restrict__ a, float* __restrict__ b, int Ntot)
{
    int c = threadIdx.x;
    float inv_n = 1.0f / (float)Ntot;
    float mu = sum[c] * inv_n;
    float var = sumsq[c] * inv_n - mu * mu;
    float ai = gamma[c] * rsqrtf(var + BN_EPS);
    a[c] = ai;
    b[c] = beta[c] - mu * ai;
}

// ---------------------------------------------------------------- fused BN-apply + fc2b + log_softmax
__global__ __launch_bounds__(256) void fc2b_fused_kernel(
    const short* __restrict__ h, const float* __restrict__ bn_a, const float* __restrict__ bn_b,
    const float* __restrict__ W, const float* __restrict__ bias,
    float* __restrict__ out, int Ntot)
{
    __shared__ float Ws[BN_DIM][N_LABELS + 1];
    __shared__ float as[BN_DIM], bs[BN_DIM];
    for (int i = threadIdx.x; i < BN_DIM * N_LABELS; i += 256) {
        int k = i / N_LABELS, j = i - k * N_LABELS;
        Ws[k][j] = W[i];
    }
    if (threadIdx.x < BN_DIM) {
        as[threadIdx.x] = bn_a[threadIdx.x];
        bs[threadIdx.x] = bn_b[threadIdx.x];
    }
    __syncthreads();

    int r = blockIdx.x * 256 + threadIdx.x;
    if (r >= Ntot) return;

    float acc[N_LABELS];
    #pragma unroll
    for (int j = 0; j < N_LABELS; j++) acc[j] = bias[j];

    const short* hr = h + (size_t)r * BN_DIM;
    #pragma unroll
    for (int k0 = 0; k0 < BN_DIM; k0 += 8) {
        bf16x8 hv = *(const bf16x8*)(hr + k0);
        #pragma unroll
        for (int t = 0; t < 8; t++) {
            float v = fmaxf(bf2f(hv[t]) * as[k0 + t] + bs[k0 + t], 0.f);
            #pragma unroll
            for (int j = 0; j < N_LABELS; j++)
                acc[j] = fmaf(v, Ws[k0 + t][j], acc[j]);
        }
    }

    float m = acc[0];
    #pragma unroll
    for (int j = 1; j < N_LABELS; j++) m = fmaxf(m, acc[j]);
    float s = 0.f;
    #pragma unroll
    for (int j = 0; j < N_LABELS; j++) s += expf(acc[j] - m);
    float lse = m + logf(s);
    float* o = out + (size_t)r * N_LABELS;
    #pragma unroll
    for (int j = 0; j < N_LABELS; j++) o[j] = acc[j] - lse;
}

// ================================================================ launch
extern "C" void kernel_launch(void* const* d_in, const int* in_sizes, int n_in,
                              void* d_out, int out_size, void* d_ws, size_t ws_size,
                              hipStream_t stream)
{
    const float* x      = (const float*)d_in[0];
    const int*   ei     = (const int*)d_in[1];
    const float* W1     = (const float*)d_in[2];
    const float* b1     = (const float*)d_in[3];
    const float* W2     = (const float*)d_in[4];
    const float* b2     = (const float*)d_in[5];
    const float* W3     = (const float*)d_in[6];
    const float* b3     = (const float*)d_in[7];
    const float* fc1_W  = (const float*)d_in[8];
    const float* fc1_b  = (const float*)d_in[9];
    const float* fc2aW  = (const float*)d_in[10];
    const float* fc2ab  = (const float*)d_in[11];
    const float* gamma  = (const float*)d_in[12];
    const float* beta   = (const float*)d_in[13];
    const float* fc2bW  = (const float*)d_in[14];
    const float* fc2bb  = (const float*)d_in[15];
    float* out = (float*)d_out;

    const int* src = ei;
    const int* dst = ei + N_EDGES;

    char* w = (char*)d_ws;
    float* dinv        = (float*)w;  w += ((size_t)N_NODES * 4 + 255) / 256 * 256;
    int*   row_start   = (int*)w;    w += ((size_t)(N_NODES + 1) * 4 + 255) / 256 * 256;
    int*   part_hist   = (int*)w;    w += ((size_t)PB * NB * 4 + 255) / 256 * 256;
    int*   bucket_total= (int*)w;    w += ((size_t)NB * 4 + 255) / 256 * 256;
    int*   bucket_base = (int*)w;    w += ((size_t)(NB + 1) * 4 + 255) / 256 * 256;
    float* bn_sum      = (float*)w;  w += 128 * 4;
    float* bn_sumsq    = (float*)w;  w += 128 * 4;
    float* bn_a        = (float*)w;  w += 128 * 4;
    float* bn_b        = (float*)w;  w += 128 * 4;
    short* Wt1         = (short*)w;  w += ((size_t)F_IN_DIM * F_IN_PAD * 2 + 255) / 256 * 256;
    short* Wt2         = (short*)w;  w += ((size_t)F_IN_DIM * F_IN_PAD * 2 + 255) / 256 * 256;
    short* Wt3         = (short*)w;  w += ((size_t)H_DIM * F_IN_PAD * 2 + 255) / 256 * 256;
    short* Wtf1        = (short*)w;  w += ((size_t)H_DIM * H_DIM * 2 + 255) / 256 * 256;
    short* Wtf2a       = (short*)w;  w += ((size_t)BN_DIM * H_DIM * 2 + 255) / 256 * 256;
    int*   src_sorted  = (int*)w;    w += ((size_t)N_EDGES * 4 + 255) / 256 * 256;
    int*   ep          = (int*)w;    w += ((size_t)N_EDGES * 4 + 255) / 256 * 256;
    short* xws100      = (short*)w;  w += ((size_t)N_NODES * F_IN_PAD * 2 + 255) / 256 * 256;
    short* agg100      = (short*)w;  w += ((size_t)N_NODES * F_IN_PAD * 2 + 255) / 256 * 256;
    short* big1        = (short*)w;  w += ((size_t)N_NODES * H_DIM * 2 + 255) / 256 * 256;
    short* big2        = (short*)w;  w += ((size_t)N_NODES * H_DIM * 2 + 255) / 256 * 256;

    // ---- CSR build (bucket-partitioned, LDS atomics) + dinv
    part_hist_kernel<<<PB, 256, 0, stream>>>(dst, part_hist, N_EDGES);
    bucket_total_kernel<<<NB, 512, 0, stream>>>(part_hist, bucket_total);
    bucket_scan_kernel<<<1, 512, 0, stream>>>(bucket_total, bucket_base);
    part_offset_kernel<<<NB, 512, 0, stream>>>(part_hist, bucket_base);
    partition_kernel<<<PB, 256, 0, stream>>>(src, dst, part_hist, ep, N_EDGES);
    bucket_csr_kernel<<<NB, 256, 0, stream>>>(ep, bucket_base, row_start, dinv,
                                              src_sorted, N_NODES, N_EDGES);

    // ---- pack weights (transpose + bf16 + zero-pad K), single launch
    pack_all<<<570, 256, 0, stream>>>(W1, W2, W3, fc1_W, fc2aW, Wt1, Wt2, Wt3, Wtf1, Wtf2a);

    const int nTB = ((N_NODES + 63) / 64 + 3) / 4;   // 391 blocks of 4 waves x 64 rows
    int gatherBlocks = (N_NODES * 16 + 255) / 256;

    // ---- conv1: xw = clip(x) @ W1, rowscale dinv -> xws100; gather -> h1 (agg100)
    gemm_reg<0, 7, 4><<<dim3(nTB, 1), 256, 0, stream>>>(
        x, Wt1, nullptr, dinv, xws100, N_NODES, F_IN_DIM, F_IN_PAD, F_IN_DIM,
        F_IN_DIM, F_IN_PAD, 0);
    gather_kernel<F_IN_DIM, F_IN_PAD, 16, 0><<<gatherBlocks, 256, 0, stream>>>(
        xws100, row_start, src_sorted, dinv, b1, agg100, N_NODES);

    // ---- conv2: xw = h1 @ W2, rowscale dinv -> xws100; gather (postscale dinv) -> h2' (agg100)
    gemm_reg<1, 7, 4><<<dim3(nTB, 1), 256, 0, stream>>>(
        agg100, Wt2, nullptr, dinv, xws100, N_NODES, F_IN_DIM, F_IN_PAD, F_IN_DIM,
        F_IN_PAD, F_IN_PAD, 0);
    gather_kernel<F_IN_DIM, F_IN_PAD, 16, 1><<<gatherBlocks, 256, 0, stream>>>(
        xws100, row_start, src_sorted, dinv, b2, agg100, N_NODES);

    // ---- conv3 (aggregate-first): g = dinv_d*(sum h2' + self) -> xws100; h3 = relu(g@W3+b3) -> big1
    gather_kernel<F_IN_DIM, F_IN_PAD, 16, 2><<<gatherBlocks, 256, 0, stream>>>(
        agg100, row_start, src_sorted, dinv, nullptr, xws100, N_NODES);
    gemm_reg<1, 8, 4><<<dim3(nTB, 2), 256, 0, stream>>>(
        xws100, Wt3, b3, nullptr, big1, N_NODES, F_IN_DIM, F_IN_PAD, H_DIM,
        F_IN_PAD, H_DIM, 1);

    // ---- fc1: 256 -> 256, relu -> big2
    gemm_reg<1, 8, 8><<<dim3(nTB, 2), 256, 0, stream>>>(
        big1, Wtf1, fc1_b, nullptr, big2, N_NODES, H_DIM, H_DIM, H_DIM,
        H_DIM, H_DIM, 1);

    // ---- fc2a: 256 -> 128 -> big1 (bf16, stride 128)
    gemm_reg<1, 8, 8><<<dim3(nTB, 1), 256, 0, stream>>>(
        big2, Wtf2a, fc2ab, nullptr, big1, N_NODES, H_DIM, H_DIM, BN_DIM,
        H_DIM, BN_DIM, 0);

    // ---- BN stats (bf16 input)
    hipMemsetAsync(bn_sum, 0, 2 * 128 * 4, stream);
    bn_stats_kernel<<<512, 256, 0, stream>>>(big1, bn_sum, bn_sumsq, N_NODES);
    bn_finalize_kernel<<<1, 128, 0, stream>>>(bn_sum, bn_sumsq, gamma, beta, bn_a, bn_b, N_NODES);

    // ---- fused BN-apply + fc2b + log_softmax -> out
    fc2b_fused_kernel<<<(N_NODES + 255) / 256, 256, 0, stream>>>(
        big1, bn_a, bn_b, fc2bW, fc2bb, out, N_NODES);
}

// Round 11
// 725.311 us; speedup vs baseline: 1.1601x; 1.1601x over previous
//
#include <hip/hip_runtime.h>
#include <hip/hip_bf16.h>

#define N_NODES 100000
#define N_EDGES 1600000
#define F_IN_DIM 100
#define F_IN_PAD 104     // padded bf16 row stride (13 x 16B chunks)
#define H_DIM 256
#define BN_DIM 128
#define N_LABELS 19
#define BN_EPS 1e-5f

// bucket-partitioned CSR build
#define BUCKET_SHIFT 8
#define NB 391           // ceil(100000 / 256) buckets of 256 nodes
#define EPB 4096         // edges per partition block
#define PB 391           // ceil(1600000 / 4096) partition blocks

typedef __attribute__((ext_vector_type(8))) short bf16x8;   // 4 VGPRs, MFMA A/B frag / 16B
typedef __attribute__((ext_vector_type(4))) short s16x4;    // 8B
typedef __attribute__((ext_vector_type(4))) float f32x4;    // MFMA C/D frag

static __device__ inline short f2bf(float f) {
    __hip_bfloat16 h = __float2bfloat16(f);
    return *(short*)&h;
}
static __device__ inline float bf2f(short s) {
    unsigned u = ((unsigned)(unsigned short)s) << 16;
    return __builtin_bit_cast(float, u);
}

// ---------------------------------------------------------------- CSR build (bucketed)
__global__ __launch_bounds__(256) void part_hist_kernel(const int* __restrict__ dst,
                                                        int* __restrict__ part_hist, int E)
{
    __shared__ int h[NB];
    int tid = threadIdx.x;
    for (int i = tid; i < NB; i += 256) h[i] = 0;
    __syncthreads();
    int base = blockIdx.x * EPB;
    int end = min(base + EPB, E);
    for (int e = base + tid; e < end; e += 256)
        atomicAdd(&h[dst[e] >> BUCKET_SHIFT], 1);
    __syncthreads();
    for (int i = tid; i < NB; i += 256) part_hist[blockIdx.x * NB + i] = h[i];
}

__global__ __launch_bounds__(512) void bucket_total_kernel(const int* __restrict__ part_hist,
                                                           int* __restrict__ bucket_total)
{
    __shared__ int ls[512];
    int b = blockIdx.x;
    int s = 0;
    for (int p = threadIdx.x; p < PB; p += 512) s += part_hist[p * NB + b];
    ls[threadIdx.x] = s;
    __syncthreads();
    for (int off = 256; off > 0; off >>= 1) {
        if (threadIdx.x < off) ls[threadIdx.x] += ls[threadIdx.x + off];
        __syncthreads();
    }
    if (threadIdx.x == 0) bucket_total[b] = ls[0];
}

__global__ __launch_bounds__(512) void bucket_scan_kernel(const int* __restrict__ bucket_total,
                                                          int* __restrict__ bucket_base)
{
    __shared__ int ls[512];
    int tid = threadIdx.x;
    ls[tid] = (tid < NB) ? bucket_total[tid] : 0;
    __syncthreads();
    for (int off = 1; off < 512; off <<= 1) {
        int v = ls[tid];
        int add = (tid >= off) ? ls[tid - off] : 0;
        __syncthreads();
        ls[tid] = v + add;
        __syncthreads();
    }
    if (tid < NB) bucket_base[tid] = (tid > 0) ? ls[tid - 1] : 0;
    if (tid == 0) bucket_base[NB] = ls[NB - 1];
}

__global__ __launch_bounds__(512) void part_offset_kernel(int* __restrict__ part_hist,
                                                          const int* __restrict__ bucket_base)
{
    __shared__ int ls[512];
    int b = blockIdx.x;
    int tid = threadIdx.x;
    int v = (tid < PB) ? part_hist[tid * NB + b] : 0;
    ls[tid] = v;
    __syncthreads();
    for (int off = 1; off < 512; off <<= 1) {
        int x = ls[tid];
        int add = (tid >= off) ? ls[tid - off] : 0;
        __syncthreads();
        ls[tid] = x + add;
        __syncthreads();
    }
    if (tid < PB) part_hist[tid * NB + b] = bucket_base[b] + ((tid > 0) ? ls[tid - 1] : 0);
}

__global__ __launch_bounds__(256) void partition_kernel(const int* __restrict__ src,
                                                        const int* __restrict__ dst,
                                                        const int* __restrict__ part_hist,
                                                        int* __restrict__ ep, int E)
{
    __shared__ int cur[NB];
    int tid = threadIdx.x;
    for (int i = tid; i < NB; i += 256) cur[i] = part_hist[blockIdx.x * NB + i];
    __syncthreads();
    int base = blockIdx.x * EPB;
    int end = min(base + EPB, E);
    for (int e = base + tid; e < end; e += 256) {
        int d = dst[e];
        int s = src[e];
        int pos = atomicAdd(&cur[d >> BUCKET_SHIFT], 1);
        ep[pos] = (s << 8) | (d & 255);
    }
}

__global__ __launch_bounds__(256) void bucket_csr_kernel(const int* __restrict__ ep,
                                                         const int* __restrict__ bucket_base,
                                                         int* __restrict__ row_start,
                                                         float* __restrict__ dinv,
                                                         int* __restrict__ src_sorted, int N, int E)
{
    __shared__ int h[256], sc[256], cur[256];
    int b = blockIdx.x;
    int tid = threadIdx.x;
    int e0 = bucket_base[b], e1 = bucket_base[b + 1];
    int node0 = b << BUCKET_SHIFT;
    int nn = min(256, N - node0);

    h[tid] = 0;
    __syncthreads();
    for (int e = e0 + tid; e < e1; e += 256)
        atomicAdd(&h[ep[e] & 255], 1);
    __syncthreads();

    sc[tid] = h[tid];
    __syncthreads();
    for (int off = 1; off < 256; off <<= 1) {
        int v = sc[tid];
        int add = (tid >= off) ? sc[tid - off] : 0;
        __syncthreads();
        sc[tid] = v + add;
        __syncthreads();
    }
    int excl = e0 + ((tid > 0) ? sc[tid - 1] : 0);
    if (tid < nn) {
        row_start[node0 + tid] = excl;
        dinv[node0 + tid] = rsqrtf((float)h[tid] + 1.0f);
    }
    cur[tid] = excl;
    __syncthreads();
    for (int e = e0 + tid; e < e1; e += 256) {
        int p = ep[e];
        int pos = atomicAdd(&cur[p & 255], 1);
        src_sorted[pos] = ((unsigned)p) >> 8;
    }
    if (b == 0 && tid == 0) row_start[N] = E;
}

// ---------------------------------------------------------------- weight pack (all 5 in one)
__global__ __launch_bounds__(256) void pack_all(
    const float* __restrict__ W1, const float* __restrict__ W2, const float* __restrict__ W3,
    const float* __restrict__ Wf1, const float* __restrict__ Wf2a,
    short* __restrict__ Wt1, short* __restrict__ Wt2, short* __restrict__ Wt3,
    short* __restrict__ Wtf1, short* __restrict__ Wtf2a)
{
    int idx = blockIdx.x * 256 + threadIdx.x;
    const float* W; short* Wt; int K, N, Kp, local;
    if (idx < 10400)       { W = W1;   Wt = Wt1;   K = 100; N = 100; Kp = 104; local = idx; }
    else if (idx < 20800)  { W = W2;   Wt = Wt2;   K = 100; N = 100; Kp = 104; local = idx - 10400; }
    else if (idx < 47424)  { W = W3;   Wt = Wt3;   K = 100; N = 256; Kp = 104; local = idx - 20800; }
    else if (idx < 112960) { W = Wf1;  Wt = Wtf1;  K = 256; N = 256; Kp = 256; local = idx - 47424; }
    else if (idx < 145728) { W = Wf2a; Wt = Wtf2a; K = 256; N = 128; Kp = 256; local = idx - 112960; }
    else return;
    int n = local / Kp, k = local - n * Kp;
    Wt[local] = (k < K) ? f2bf(W[(size_t)k * N + n]) : (short)0;
}

// ---------------------------------------------------------------- one-shot MFMA GEMM (K<=104)
// Entire K staged in LDS -> exactly ONE barrier per block lifetime.
// 128x128 tile, 4 waves, each 64x64 = 4x4 frags; kc=3 covers k=96..103 via quad0,
// quads 1-3 at kc=3 use zero frags (pad region).
template<int ABF16>
__global__ __launch_bounds__(256) void gemm_oneshot(
    const void* __restrict__ Av, const short* __restrict__ Wt,
    const float* __restrict__ bias, const float* __restrict__ rowscale,
    short* __restrict__ C, int M, int Nout, int strideA, int strideC, int relu)
{
    __shared__ __align__(16) short As[128][F_IN_PAD];
    __shared__ __align__(16) short Bs[128][F_IN_PAD];
    int tid = threadIdx.x;
    int rowBase = blockIdx.x * 128;
    int colBase = blockIdx.y * 128;

    if (ABF16) {
        const short* A = (const short*)Av;
        for (int ch = tid; ch < 128 * 13; ch += 256) {
            int r = ch / 13, c8 = (ch - r * 13) * 8;
            int gr = rowBase + r;
            bf16x8 o = (bf16x8){0,0,0,0,0,0,0,0};
            if (gr < M) o = *(const bf16x8*)(A + (size_t)gr * strideA + c8);
            *(bf16x8*)(&As[r][c8]) = o;
        }
    } else {
        const float* A = (const float*)Av;
        for (int ch = tid; ch < 128 * 25; ch += 256) {
            int r = ch / 25, c4 = (ch - r * 25) * 4;
            int gr = rowBase + r;
            float4 v = make_float4(0.f, 0.f, 0.f, 0.f);
            if (gr < M) v = *(const float4*)(A + (size_t)gr * strideA + c4);
            v.x = fminf(fmaxf(v.x, -0.4f), 0.4f);
            v.y = fminf(fmaxf(v.y, -0.4f), 0.4f);
            v.z = fminf(fmaxf(v.z, -0.4f), 0.4f);
            v.w = fminf(fmaxf(v.w, -0.4f), 0.4f);
            s16x4 o = (s16x4){f2bf(v.x), f2bf(v.y), f2bf(v.z), f2bf(v.w)};
            *(s16x4*)(&As[r][c4]) = o;
        }
        for (int r = tid; r < 128; r += 256)     // zero pad cols 100..103
            *(s16x4*)(&As[r][100]) = (s16x4){0, 0, 0, 0};
    }
    for (int ch = tid; ch < 128 * 13; ch += 256) {
        int n = ch / 13, c8 = (ch - n * 13) * 8;
        int gn = colBase + n;
        bf16x8 o = (bf16x8){0,0,0,0,0,0,0,0};
        if (gn < Nout) o = *(const bf16x8*)(Wt + (size_t)gn * F_IN_PAD + c8);
        *(bf16x8*)(&Bs[n][c8]) = o;
    }
    __syncthreads();   // the only barrier

    int wid = tid >> 6;
    int lane = tid & 63;
    int quad = lane >> 4, l15 = lane & 15;
    int wave_m = (wid & 1) * 64;
    int wave_n = (wid >> 1) * 64;

    f32x4 acc[4][4];
    #pragma unroll
    for (int i = 0; i < 4; i++)
        #pragma unroll
        for (int j = 0; j < 4; j++)
            acc[i][j] = (f32x4){0.f, 0.f, 0.f, 0.f};

    #pragma unroll
    for (int kc = 0; kc < 4; kc++) {
        int off = kc * 32 + quad * 8;
        bool ok = (off + 8 <= F_IN_PAD);     // false only for kc=3, quad>=1 (pad)
        bf16x8 a[4], b[4];
        #pragma unroll
        for (int im = 0; im < 4; im++)
            a[im] = ok ? *(const bf16x8*)(&As[wave_m + im * 16 + l15][off])
                       : (bf16x8){0,0,0,0,0,0,0,0};
        #pragma unroll
        for (int in = 0; in < 4; in++)
            b[in] = ok ? *(const bf16x8*)(&Bs[wave_n + in * 16 + l15][off])
                       : (bf16x8){0,0,0,0,0,0,0,0};
        #pragma unroll
        for (int im = 0; im < 4; im++)
            #pragma unroll
            for (int in = 0; in < 4; in++)
                acc[im][in] = __builtin_amdgcn_mfma_f32_16x16x32_bf16(
                    a[im], b[in], acc[im][in], 0, 0, 0);
    }

    // ---- epilogue: C/D layout col=lane&15, row=quad*4+reg
    #pragma unroll
    for (int im = 0; im < 4; im++) {
        #pragma unroll
        for (int reg = 0; reg < 4; reg++) {
            int row = rowBase + wave_m + im * 16 + quad * 4 + reg;
            if (row >= M) continue;
            float rs = rowscale ? rowscale[row] : 1.f;
            #pragma unroll
            for (int in = 0; in < 4; in++) {
                int col = colBase + wave_n + in * 16 + l15;
                if (col >= strideC) continue;
                float v = 0.f;
                if (col < Nout) {
                    v = acc[im][in][reg];
                    if (bias) v += bias[col];
                    v *= rs;
                    if (relu) v = fmaxf(v, 0.f);
                }
                C[(size_t)row * strideC + col] = f2bf(v);
            }
        }
    }
}

// ---------------------------------------------------------------- pipelined MFMA GEMM (K=256)
// Round-7 structure: register prefetch, BK=64, 2 barriers/iter.
#define SAP 72   // LDS row stride in shorts
__global__ __launch_bounds__(256) void gemm_mfma(
    const short* __restrict__ A, const short* __restrict__ Wt,
    const float* __restrict__ bias, const float* __restrict__ rowscale,
    short* __restrict__ C, int M, int Kp, int Nout,
    int strideA, int strideC, int relu)
{
    __shared__ __align__(16) short As[128][SAP];
    __shared__ __align__(16) short Bs[128][SAP];

    int tid = threadIdx.x;
    int wid = tid >> 6;
    int lane = tid & 63;
    int quad = lane >> 4;
    int l15 = lane & 15;
    int wave_m = (wid & 1) * 64;
    int wave_n = (wid >> 1) * 64;
    int rowBase = blockIdx.y * 128;
    int colBase = blockIdx.x * 128;

    f32x4 acc[4][4];
    #pragma unroll
    for (int i = 0; i < 4; i++)
        #pragma unroll
        for (int j = 0; j < 4; j++)
            acc[i][j] = (f32x4){0.f, 0.f, 0.f, 0.f};

    bf16x8 pa[4], pb[4];
    int nIter = (Kp + 63) >> 6;

    auto loadA = [&](int k0) {
        #pragma unroll
        for (int i = 0; i < 4; i++) {
            int ch = tid + i * 256;
            int r = ch >> 3, c8 = (ch & 7) << 3;
            int gr = rowBase + r, gk = k0 + c8;
            bf16x8 o = (bf16x8){0,0,0,0,0,0,0,0};
            if (gr < M && gk < strideA)
                o = *(const bf16x8*)(A + (size_t)gr * strideA + gk);
            pa[i] = o;
        }
    };
    auto loadB = [&](int k0) {
        #pragma unroll
        for (int i = 0; i < 4; i++) {
            int ch = tid + i * 256;
            int n = ch >> 3, c8 = (ch & 7) << 3;
            int gn = colBase + n, gk = k0 + c8;
            bf16x8 o = (bf16x8){0,0,0,0,0,0,0,0};
            if (gn < Nout && gk < Kp)
                o = *(const bf16x8*)(Wt + (size_t)gn * Kp + gk);
            pb[i] = o;
        }
    };
    auto storeAB = [&]() {
        #pragma unroll
        for (int i = 0; i < 4; i++) {
            int ch = tid + i * 256;
            int r = ch >> 3, c8 = (ch & 7) << 3;
            *(bf16x8*)(&As[r][c8]) = pa[i];
            *(bf16x8*)(&Bs[r][c8]) = pb[i];
        }
    };

    loadA(0); loadB(0);
    for (int it = 0; it < nIter; ++it) {
        if (it > 0) __syncthreads();
        storeAB();
        __syncthreads();
        if (it + 1 < nIter) { loadA((it + 1) << 6); loadB((it + 1) << 6); }
        #pragma unroll
        for (int ks = 0; ks < 2; ks++) {
            bf16x8 a[4], b[4];
            #pragma unroll
            for (int im = 0; im < 4; im++)
                a[im] = *(const bf16x8*)(&As[wave_m + im * 16 + l15][quad * 8 + ks * 32]);
            #pragma unroll
            for (int in = 0; in < 4; in++)
                b[in] = *(const bf16x8*)(&Bs[wave_n + in * 16 + l15][quad * 8 + ks * 32]);
            #pragma unroll
            for (int im = 0; im < 4; im++)
                #pragma unroll
                for (int in = 0; in < 4; in++)
                    acc[im][in] = __builtin_amdgcn_mfma_f32_16x16x32_bf16(
                        a[im], b[in], acc[im][in], 0, 0, 0);
        }
    }

    #pragma unroll
    for (int im = 0; im < 4; im++) {
        #pragma unroll
        for (int reg = 0; reg < 4; reg++) {
            int row = rowBase + wave_m + im * 16 + quad * 4 + reg;
            if (row >= M) continue;
            float rs = rowscale ? rowscale[row] : 1.f;
            #pragma unroll
            for (int in = 0; in < 4; in++) {
                int col = colBase + wave_n + in * 16 + l15;
                if (col >= strideC) continue;
                float v = 0.f;
                if (col < Nout) {
                    v = acc[im][in][reg];
                    if (bias) v += bias[col];
                    v *= rs;
                    if (relu) v = fmaxf(v, 0.f);
                }
                C[(size_t)row * strideC + col] = f2bf(v);
            }
        }
    }
}

// ---------------------------------------------------------------- gather aggregation (bf16)
// MODE 0: out = relu(di*(acc+self) + bias)           (conv1)
// MODE 1: out = di * relu(di*(acc+self) + bias)      (conv2: pre-folds next layer's dinv_s)
// MODE 2: out = di * (acc+self)                      (conv3 pre-aggregation)
template<int F, int STRIDE, int T, int MODE>
__global__ void gather_kernel(const short* __restrict__ xws,
                              const int* __restrict__ row_start,
                              const int* __restrict__ src_sorted,
                              const float* __restrict__ dinv,
                              const float* __restrict__ bias,
                              short* __restrict__ out, int n)
{
    constexpr int CHUNKS = STRIDE / 8;
    int group = (blockIdx.x * blockDim.x + threadIdx.x) / T;
    int lane = threadIdx.x % T;
    if (group >= n) return;
    int d = group;
    int e0 = row_start[d], e1 = row_start[d + 1];
    bool active = (lane < CHUNKS);
    int coff = lane * 8;
    float acc[8] = {};
    for (int e = e0; e < e1; e++) {
        int s = src_sorted[e];
        if (active) {
            bf16x8 v = *(const bf16x8*)(xws + (size_t)s * STRIDE + coff);
            #pragma unroll
            for (int j = 0; j < 8; j++) acc[j] += bf2f(v[j]);
        }
    }
    if (active) {
        bf16x8 xv = *(const bf16x8*)(xws + (size_t)d * STRIDE + coff);
        float di = dinv[d];
        bf16x8 o;
        #pragma unroll
        for (int j = 0; j < 8; j++) {
            int col = coff + j;
            float v = 0.f;
            if (col < F) {
                v = di * (acc[j] + bf2f(xv[j]));
                if (MODE == 0) v = fmaxf(v + bias[col], 0.f);
                if (MODE == 1) v = di * fmaxf(v + bias[col], 0.f);
            }
            o[j] = f2bf(v);
        }
        *(bf16x8*)(out + (size_t)d * STRIDE + coff) = o;
    }
}

// ---------------------------------------------------------------- BN stats (bf16 input)
__global__ void bn_stats_kernel(const short* __restrict__ h,
                                float* __restrict__ sum, float* __restrict__ sumsq, int Ntot)
{
    int c = threadIdx.x & 127;
    int rpb = blockDim.x >> 7;
    int r0 = blockIdx.x * rpb + (threadIdx.x >> 7);
    int stride = gridDim.x * rpb;
    float s = 0.f, ss = 0.f;
    for (int r = r0; r < Ntot; r += stride) {
        float v = bf2f(h[(size_t)r * BN_DIM + c]);
        s += v; ss += v * v;
    }
    __shared__ float ls[256], lss[256];
    ls[threadIdx.x] = s; lss[threadIdx.x] = ss;
    __syncthreads();
    if (threadIdx.x < 128) {
        s = ls[threadIdx.x] + ls[threadIdx.x + 128];
        ss = lss[threadIdx.x] + lss[threadIdx.x + 128];
        atomicAdd(&sum[c], s);
        atomicAdd(&sumsq[c], ss);
    }
}

__global__ void bn_finalize_kernel(const float* __restrict__ sum, const float* __restrict__ sumsq,
                                   const float* __restrict__ gamma, const float* __restrict__ beta,
                                   float* __restrict__ a, float* __restrict__ b, int Ntot)
{
    int c = threadIdx.x;
    float inv_n = 1.0f / (float)Ntot;
    float mu = sum[c] * inv_n;
    float var = sumsq[c] * inv_n - mu * mu;
    float ai = gamma[c] * rsqrtf(var + BN_EPS);
    a[c] = ai;
    b[c] = beta[c] - mu * ai;
}

// ---------------------------------------------------------------- fused BN-apply + fc2b + log_softmax
__global__ __launch_bounds__(256) void fc2b_fused_kernel(
    const short* __restrict__ h, const float* __restrict__ bn_a, const float* __restrict__ bn_b,
    const float* __restrict__ W, const float* __restrict__ bias,
    float* __restrict__ out, int Ntot)
{
    __shared__ float Ws[BN_DIM][N_LABELS + 1];
    __shared__ float as[BN_DIM], bs[BN_DIM];
    for (int i = threadIdx.x; i < BN_DIM * N_LABELS; i += 256) {
        int k = i / N_LABELS, j = i - k * N_LABELS;
        Ws[k][j] = W[i];
    }
    if (threadIdx.x < BN_DIM) {
        as[threadIdx.x] = bn_a[threadIdx.x];
        bs[threadIdx.x] = bn_b[threadIdx.x];
    }
    __syncthreads();

    int r = blockIdx.x * 256 + threadIdx.x;
    if (r >= Ntot) return;

    float acc[N_LABELS];
    #pragma unroll
    for (int j = 0; j < N_LABELS; j++) acc[j] = bias[j];

    const short* hr = h + (size_t)r * BN_DIM;
    #pragma unroll
    for (int k0 = 0; k0 < BN_DIM; k0 += 8) {
        bf16x8 hv = *(const bf16x8*)(hr + k0);
        #pragma unroll
        for (int t = 0; t < 8; t++) {
            float v = fmaxf(bf2f(hv[t]) * as[k0 + t] + bs[k0 + t], 0.f);
            #pragma unroll
            for (int j = 0; j < N_LABELS; j++)
                acc[j] = fmaf(v, Ws[k0 + t][j], acc[j]);
        }
    }

    float m = acc[0];
    #pragma unroll
    for (int j = 1; j < N_LABELS; j++) m = fmaxf(m, acc[j]);
    float s = 0.f;
    #pragma unroll
    for (int j = 0; j < N_LABELS; j++) s += expf(acc[j] - m);
    float lse = m + logf(s);
    float* o = out + (size_t)r * N_LABELS;
    #pragma unroll
    for (int j = 0; j < N_LABELS; j++) o[j] = acc[j] - lse;
}

// ================================================================ launch
extern "C" void kernel_launch(void* const* d_in, const int* in_sizes, int n_in,
                              void* d_out, int out_size, void* d_ws, size_t ws_size,
                              hipStream_t stream)
{
    const float* x      = (const float*)d_in[0];
    const int*   ei     = (const int*)d_in[1];
    const float* W1     = (const float*)d_in[2];
    const float* b1     = (const float*)d_in[3];
    const float* W2     = (const float*)d_in[4];
    const float* b2     = (const float*)d_in[5];
    const float* W3     = (const float*)d_in[6];
    const float* b3     = (const float*)d_in[7];
    const float* fc1_W  = (const float*)d_in[8];
    const float* fc1_b  = (const float*)d_in[9];
    const float* fc2aW  = (const float*)d_in[10];
    const float* fc2ab  = (const float*)d_in[11];
    const float* gamma  = (const float*)d_in[12];
    const float* beta   = (const float*)d_in[13];
    const float* fc2bW  = (const float*)d_in[14];
    const float* fc2bb  = (const float*)d_in[15];
    float* out = (float*)d_out;

    const int* src = ei;
    const int* dst = ei + N_EDGES;

    char* w = (char*)d_ws;
    float* dinv        = (float*)w;  w += ((size_t)N_NODES * 4 + 255) / 256 * 256;
    int*   row_start   = (int*)w;    w += ((size_t)(N_NODES + 1) * 4 + 255) / 256 * 256;
    int*   part_hist   = (int*)w;    w += ((size_t)PB * NB * 4 + 255) / 256 * 256;
    int*   bucket_total= (int*)w;    w += ((size_t)NB * 4 + 255) / 256 * 256;
    int*   bucket_base = (int*)w;    w += ((size_t)(NB + 1) * 4 + 255) / 256 * 256;
    float* bn_sum      = (float*)w;  w += 128 * 4;
    float* bn_sumsq    = (float*)w;  w += 128 * 4;
    float* bn_a        = (float*)w;  w += 128 * 4;
    float* bn_b        = (float*)w;  w += 128 * 4;
    short* Wt1         = (short*)w;  w += ((size_t)F_IN_DIM * F_IN_PAD * 2 + 255) / 256 * 256;
    short* Wt2         = (short*)w;  w += ((size_t)F_IN_DIM * F_IN_PAD * 2 + 255) / 256 * 256;
    short* Wt3         = (short*)w;  w += ((size_t)H_DIM * F_IN_PAD * 2 + 255) / 256 * 256;
    short* Wtf1        = (short*)w;  w += ((size_t)H_DIM * H_DIM * 2 + 255) / 256 * 256;
    short* Wtf2a       = (short*)w;  w += ((size_t)BN_DIM * H_DIM * 2 + 255) / 256 * 256;
    int*   src_sorted  = (int*)w;    w += ((size_t)N_EDGES * 4 + 255) / 256 * 256;
    int*   ep          = (int*)w;    w += ((size_t)N_EDGES * 4 + 255) / 256 * 256;
    short* xws100      = (short*)w;  w += ((size_t)N_NODES * F_IN_PAD * 2 + 255) / 256 * 256;
    short* agg100      = (short*)w;  w += ((size_t)N_NODES * F_IN_PAD * 2 + 255) / 256 * 256;
    short* big1        = (short*)w;  w += ((size_t)N_NODES * H_DIM * 2 + 255) / 256 * 256;
    short* big2        = (short*)w;  w += ((size_t)N_NODES * H_DIM * 2 + 255) / 256 * 256;

    // ---- CSR build (bucket-partitioned, LDS atomics) + dinv
    part_hist_kernel<<<PB, 256, 0, stream>>>(dst, part_hist, N_EDGES);
    bucket_total_kernel<<<NB, 512, 0, stream>>>(part_hist, bucket_total);
    bucket_scan_kernel<<<1, 512, 0, stream>>>(bucket_total, bucket_base);
    part_offset_kernel<<<NB, 512, 0, stream>>>(part_hist, bucket_base);
    partition_kernel<<<PB, 256, 0, stream>>>(src, dst, part_hist, ep, N_EDGES);
    bucket_csr_kernel<<<NB, 256, 0, stream>>>(ep, bucket_base, row_start, dinv,
                                              src_sorted, N_NODES, N_EDGES);

    // ---- pack weights (transpose + bf16 + zero-pad K), single launch
    pack_all<<<570, 256, 0, stream>>>(W1, W2, W3, fc1_W, fc2aW, Wt1, Wt2, Wt3, Wtf1, Wtf2a);

    const int nOne = (N_NODES + 127) / 128;   // 782
    int gatherBlocks = (N_NODES * 16 + 255) / 256;

    // ---- conv1: xw = clip(x) @ W1, rowscale dinv -> xws100; gather -> h1 (agg100)
    gemm_oneshot<0><<<dim3(nOne, 1), 256, 0, stream>>>(
        x, Wt1, nullptr, dinv, xws100, N_NODES, F_IN_DIM, F_IN_DIM, F_IN_PAD, 0);
    gather_kernel<F_IN_DIM, F_IN_PAD, 16, 0><<<gatherBlocks, 256, 0, stream>>>(
        xws100, row_start, src_sorted, dinv, b1, agg100, N_NODES);

    // ---- conv2: xw = h1 @ W2, rowscale dinv -> xws100; gather (postscale dinv) -> h2' (agg100)
    gemm_oneshot<1><<<dim3(nOne, 1), 256, 0, stream>>>(
        agg100, Wt2, nullptr, dinv, xws100, N_NODES, F_IN_DIM, F_IN_PAD, F_IN_PAD, 0);
    gather_kernel<F_IN_DIM, F_IN_PAD, 16, 1><<<gatherBlocks, 256, 0, stream>>>(
        xws100, row_start, src_sorted, dinv, b2, agg100, N_NODES);

    // ---- conv3 (aggregate-first): g = dinv_d*(sum h2' + self) -> xws100; h3 = relu(g@W3+b3) -> big1
    gather_kernel<F_IN_DIM, F_IN_PAD, 16, 2><<<gatherBlocks, 256, 0, stream>>>(
        agg100, row_start, src_sorted, dinv, nullptr, xws100, N_NODES);
    gemm_oneshot<1><<<dim3(nOne, 2), 256, 0, stream>>>(
        xws100, Wt3, b3, nullptr, big1, N_NODES, H_DIM, F_IN_PAD, H_DIM, 1);

    // ---- fc1: 256 -> 256, relu -> big2 (pipelined K=256 kernel)
    gemm_mfma<<<dim3(2, nOne), 256, 0, stream>>>(
        big1, Wtf1, fc1_b, nullptr, big2, N_NODES, H_DIM, H_DIM, H_DIM, H_DIM, 1);

    // ---- fc2a: 256 -> 128 -> big1 (bf16, stride 128)
    gemm_mfma<<<dim3(1, nOne), 256, 0, stream>>>(
        big2, Wtf2a, fc2ab, nullptr, big1, N_NODES, H_DIM, BN_DIM, H_DIM, BN_DIM, 0);

    // ---- BN stats (bf16 input)
    hipMemsetAsync(bn_sum, 0, 2 * 128 * 4, stream);
    bn_stats_kernel<<<512, 256, 0, stream>>>(big1, bn_sum, bn_sumsq, N_NODES);
    bn_finalize_kernel<<<1, 128, 0, stream>>>(bn_sum, bn_sumsq, gamma, beta, bn_a, bn_b, N_NODES);

    // ---- fused BN-apply + fc2b + log_softmax -> out
    fc2b_fused_kernel<<<(N_NODES + 255) / 256, 256, 0, stream>>>(
        big1, bn_a, bn_b, fc2bW, fc2bb, out, N_NODES);
}